// Round 6
// baseline (235.678 us; speedup 1.0000x reference)
//
#include <hip/hip_runtime.h>

// ForwardTransformLayer: lifting step with circular 8-tap convolutions.
//   even = in[:, ::2], odd = in[:, 1::2]            (row length 8192 -> 4096 each)
//   odd_out[k]  = odd[k]  - sum_j even[(k-j) mod n] * wavelet[j]
//   even_out[k] = even[k] - sum_j odd[(k-j)  mod n] * scaling[j]
//   wavelet[j] = scaling_rec[7-j] * (j odd ? -1 : +1)
// d_out layout: even_out (rows*4096) then odd_out (rows*4096), row-major.
//
// R9 design: experiment matrix {sparse,dense} x {one-shot,long-lived}:
// R3 sparse/one-shot 79.6, R4 sparse/pipelined 82, R8 dense/one-shot ~75.
// The two ceiling-hitting kernels on this chip (poison fill 6.7 TB/s @ 9%
// occupancy, m13 copy 6.29 TB/s) are BOTH dense AND long-lived grid-stride.
// R8's waves still die after one load->wait->compute->store round trip.
// R9 = R8's exact math, restructured: 2048 resident blocks, each thread
// keeps a fixed row-local float4 index f and marches 16 row-slices
// (row = rowbase + 256*it), with an explicit 2-deep A/B prefetch pipeline
// so the next slice's 5 loads are in flight under the current slice's
// FMAs + stores. All array indices static (rule: runtime-indexed vectors
// spill to scratch); wrap masks are per-thread constants.

#define COLS       8192
#define HALF       4096                       // pairs per row
#define F4_PER_ROW 2048                       // float4s per row (2 pairs each)
#define NTHREADS   256
#define ITERS      16                         // row-slices per thread

__global__ __launch_bounds__(NTHREADS) void fwd_dwt_kernel(
    const float* __restrict__ input,
    const float* __restrict__ scaling,
    const float* __restrict__ scaling_rec,
    float* __restrict__ out,
    int rows)
{
    const int g       = blockIdx.x * NTHREADS + threadIdx.x;
    const int f       = g & (F4_PER_ROW - 1);    // row-local float4 index (fixed)
    const int rowbase = g >> 11;                 // starting row (0..rs-1)
    const int rs      = rows / ITERS;            // row stride per iteration (256)

    // Circular-window source indices (per-thread constants).
    const int m1 = (f - 1) & (F4_PER_ROW - 1);
    const int m2 = (f - 2) & (F4_PER_ROW - 1);
    const int m3 = (f - 3) & (F4_PER_ROW - 1);
    const int m4 = (f - 4) & (F4_PER_ROW - 1);

    // Filters (uniform scalar loads -> SGPRs).
    float w[8], sc[8];
#pragma unroll
    for (int j = 0; j < 8; ++j) {
        w[j]  = scaling_rec[7 - j] * ((j & 1) ? -1.0f : 1.0f);
        sc[j] = scaling[j];
    }

    struct W5 { float4 v, h1, h2, h3, h4; };

    auto LOAD = [&](const float4* base) {
        W5 r;
        r.v  = base[f];
        r.h1 = base[m1];
        r.h2 = base[m2];
        r.h3 = base[m3];
        r.h4 = base[m4];
        return r;
    };

    auto CRUNCH = [&](const W5& x, float* poe, float* pod) {
        // Window: pair (k0-7+i) -> pe[i]/po[i], i = 0..8.  k0 = 2*f.
        float pe[9], po[9];
        pe[0] = x.h4.z; po[0] = x.h4.w;
        pe[1] = x.h3.x; po[1] = x.h3.y;  pe[2] = x.h3.z; po[2] = x.h3.w;
        pe[3] = x.h2.x; po[3] = x.h2.y;  pe[4] = x.h2.z; po[4] = x.h2.w;
        pe[5] = x.h1.x; po[5] = x.h1.y;  pe[6] = x.h1.z; po[6] = x.h1.w;
        pe[7] = x.v.x;  po[7] = x.v.y;   pe[8] = x.v.z;  po[8] = x.v.w;

        float eo0 = pe[7], oo0 = po[7], eo1 = pe[8], oo1 = po[8];
#pragma unroll
        for (int j = 0; j < 8; ++j) {
            eo0 -= po[7 - j] * sc[j];
            oo0 -= pe[7 - j] * w[j];
            eo1 -= po[8 - j] * sc[j];
            oo1 -= pe[8 - j] * w[j];
        }
        // Dense stores: lane l writes 8 B at 8*l -> contiguous 512 B/wave.
        ((float2*)poe)[0] = make_float2(eo0, eo1);
        ((float2*)pod)[0] = make_float2(oo0, oo1);
    };

    const size_t in_step  = (size_t)rs * F4_PER_ROW;   // float4s per row-slice
    const size_t out_step = (size_t)rs * HALF;         // floats per row-slice

    const float4* ip = (const float4*)input + (size_t)rowbase * F4_PER_ROW;
    float* pe = out + (size_t)rowbase * HALF + 2 * f;  // even plane
    float* po = pe + (size_t)rows * HALF;              // odd plane (same offsets)

    // 2-deep software pipeline: B prefetches while A computes, and vice versa.
    W5 A = LOAD(ip);
#pragma unroll 1
    for (int it = 0; it < ITERS; it += 2) {
        const float4* ip1 = ip + in_step;
        W5 B = LOAD(ip1);                       // prefetch slice it+1

        CRUNCH(A, pe, po);                      // compute/store slice it
        pe += out_step; po += out_step;

        const float4* ip2 = ip1 + in_step;
        if (it + 2 < ITERS) A = LOAD(ip2);      // prefetch slice it+2

        CRUNCH(B, pe, po);                      // compute/store slice it+1
        pe += out_step; po += out_step;

        ip = ip2;
    }
}

extern "C" void kernel_launch(void* const* d_in, const int* in_sizes, int n_in,
                              void* d_out, int out_size, void* d_ws, size_t ws_size,
                              hipStream_t stream) {
    const float* input       = (const float*)d_in[0];
    const float* scaling     = (const float*)d_in[1];
    const float* scaling_rec = (const float*)d_in[2];
    float*       out         = (float*)d_out;

    const int rows    = in_sizes[0] / COLS;                  // 4096
    const int threads = (rows / ITERS) * F4_PER_ROW;         // 524,288
    fwd_dwt_kernel<<<threads / NTHREADS, NTHREADS, 0, stream>>>(
        input, scaling, scaling_rec, out, rows);
}